// Round 6
// baseline (225.764 us; speedup 1.0000x reference)
//
#include <hip/hip_runtime.h>
#include <hip/hip_bf16.h>
#include <cmath>
#include <cstddef>

#define N 8192
#define D 256
#define NBB 128                 // 64-row bands
#define JT 4                    // j-tiles (64 cols) per block segment
#define NBLK2 2112              // sum over bands of ceil((128-bb)/4) = 8*264

typedef __attribute__((ext_vector_type(8))) short short8;   // 8 bf16 = one MFMA A/B frag
typedef __attribute__((ext_vector_type(4))) float float4v;  // MFMA C/D frag

#define U64MAX 0xFFFFFFFFFFFFFFFFull

__device__ inline ushort f2bf(float x) {
    __hip_bfloat16 h = __float2bfloat16(x);
    return __builtin_bit_cast(ushort, h);
}
__device__ inline float bf2f(ushort u) {
    __hip_bfloat16 h = __builtin_bit_cast(__hip_bfloat16, u);
    return __bfloat162float(h);
}

// sortable pack: (monotone-uint(key) << 32) | idx  -> u64 min == (key, idx) lex argmin,
// lowest-idx tie-break. Identical to all prior passing revs.
__device__ inline unsigned long long packKI(float k, int idx) {
    unsigned u = __float_as_uint(k);
    u = (u & 0x80000000u) ? ~u : (u | 0x80000000u);
    return ((unsigned long long)u << 32) | (unsigned)idx;
}
__device__ inline unsigned long long min64(unsigned long long a, unsigned long long b) {
    return a < b ? a : b;
}

// G(n) = sum_{m=1..n} ceil(m/4): blocks in the last n bands
__device__ inline int segG(int n) { int a = n >> 2, r = n & 3; return 2 * a * (a + 1) + r * (a + 1); }

// ============================================================================
// Frag-tiled bf16 layout (unchanged): frag for (16-row group g, k-chunk k, lane)
// at ushort offset (g*8 + k)*512 + lane*8 -> wave frag load = uniform base +
// lane*16B: one coalesced 1 KB dwordx4.
// ============================================================================

// ---------------- K1: fused prep — M init, copies, sqnorm, frag-tiled bf16 hi/lo split ----
// grid MUST be 1024 x 256 (phase C uses exactly 4096 waves, one 16x32 tile each).
__global__ void prep_kernel(const float4* __restrict__ a, const float4* __restrict__ p,
                            float4* __restrict__ out, float* __restrict__ sq,
                            ushort* __restrict__ Ehi, ushort* __restrict__ Elo,
                            unsigned long long* __restrict__ M) {
    const int gsz = gridDim.x * blockDim.x;          // 262144, multiple of 64
    const int g0 = blockIdx.x * blockDim.x + threadIdx.x;
    const int total = N * D / 4;                     // 524288 float4

    // phase A: e_actv copy + per-row sqnorm (one row per wave per iter: 64 float4 = 1 row)
    for (int idx = g0; idx < total; idx += gsz) {
        float4 v = a[idx];
        out[idx] = v;
        float s = v.x * v.x + v.y * v.y + v.z * v.z + v.w * v.w;
        #pragma unroll
        for (int off = 32; off; off >>= 1) s += __shfl_down(s, off);
        if ((threadIdx.x & 63) == 0) sq[idx >> 6] = s;
    }
    // phase B: e_ap plain copy into second output slot
    for (int idx = g0; idx < total; idx += gsz) out[total + idx] = p[idx];

    // phase C: frag-tiled hi/lo split. One wave per (r16, ktc) tile of 16 rows x 32 k.
    {
        const int w = g0 >> 6;           // global wave id, 0..4095
        if (w < 4096) {
            const int lane = threadIdx.x & 63;
            const int tx = lane & 15;
            const int q  = lane >> 4;
            const int r16 = w >> 3;      // 0..511
            const int ktc = w & 7;       // 0..7
            const int row = r16 * 16 + tx;
            const float4 v0 = a[row * 64 + ktc * 8 + q * 2];
            const float4 v1 = a[row * 64 + ktc * 8 + q * 2 + 1];
            float e[8] = {v0.x, v0.y, v0.z, v0.w, v1.x, v1.y, v1.z, v1.w};
            short8 hs, ls;
            #pragma unroll
            for (int j = 0; j < 8; j++) {
                ushort h = f2bf(e[j]);
                ushort l = f2bf(e[j] - bf2f(h));
                hs[j] = (short)h;
                ls[j] = (short)l;
            }
            const size_t off = (size_t)(r16 * 8 + ktc) * 512 + lane * 8;
            *(short8*)&Ehi[off] = hs;
            *(short8*)&Elo[off] = ls;
        }
    }
    // M init
    for (int i = g0; i < N; i += gsz) M[i] = 0xFFFFFFFFFFFFFFFFull;
}

// ---------------- K2: A-register-resident band x streamed j-tiles ----------------
// Block = 64-row band (4 waves x 16 rows, A hi/lo register-resident: 64 VGPR,
// loaded ONCE) x up to 4 j-tiles of 64 cols streamed through a B chunk-dbuf.
// Up to 32 thin phases (12 MFMA each) per block amortize all prologue latency;
// B chunks are L1-shared by the 4 waves. No K-loop barriers.
// Coverage: bands bb in [0,128) x j-tiles tj in [bb,128) split into 4-tile
// segments; strict upper triangle via (jg<=ig) mask on the diagonal tile only.
// Dual-sided argmin: row-side = running packed-u64 reg min across all tiles
// (one shfl-reduce per block); col-side = per-tile q-reduce -> per-wave LDS
// slot -> merged once at block end. Keys, masks, MFMA order, packKI, tie-break
// all identical to prior passing revs -> identical argmin indices.
__launch_bounds__(256, 3)
__global__ void argmin_sym(const ushort* __restrict__ Ehi, const ushort* __restrict__ Elo,
                           const int* __restrict__ host, const float* __restrict__ sq,
                           unsigned long long* __restrict__ M) {
    // XCD swizzle (2112 = 8*264, bijective), then decode b -> (band bb, segment seg)
    const int b0 = blockIdx.x;
    const int b = (b0 & 7) * (NBLK2 / 8) + (b0 >> 3);
    int bb = 0;
    while (bb < 127 && (NBLK2 - segG(NBB - (bb + 1))) <= b) bb++;
    const int seg = b - (NBLK2 - segG(NBB - bb));
    const int tj0 = bb + 4 * seg;                 // first j-tile
    const int ntiles = min(JT, NBB - tj0);        // 1..4
    const int jr0 = tj0 * 64;                     // first col of the segment range

    __shared__ float sqB_s[256];
    __shared__ int   hostB_s[256];
    __shared__ unsigned long long colV[4][256];   // per-wave col-min slots

    const int tid = threadIdx.x;
    const int lane = tid & 63;
    const int w = tid >> 6;         // wave 0..3
    const int tx = lane & 15;       // 0..15
    const int q  = lane >> 4;       // 0..3

    const int ig0 = bb * 64 + w * 16;   // wave's first row
    const int rg  = bb * 4 + w;         // wave's 16-row frag group
    const int lo8 = lane * 8;

    // ---- B chunk double-buffer (issued early, pinned by sched_barrier) ----
    short8 bH[2][4], bL[2][4];
    auto loadB = [&](int slot, int tj, int k) {
        #pragma unroll
        for (int ct = 0; ct < 4; ct++) {
            const int o = ((tj * 4 + ct) * 8 + k) * 512 + lo8;
            bH[slot][ct] = *(const short8*)&Ehi[o];
            bL[slot][ct] = *(const short8*)&Elo[o];
        }
    };
    loadB(0, tj0, 0);   // gate of phase 0: issue first

    // ---- A resident frags: 16 rows x all 8 chunks, hi+lo (64 VGPR) ----
    short8 aH[8], aL[8];
    #pragma unroll
    for (int k = 0; k < 8; k++) {
        const int o = (rg * 8 + k) * 512 + lo8;
        aH[k] = *(const short8*)&Ehi[o];
        aL[k] = *(const short8*)&Elo[o];
    }

    // ---- per-lane row-side scalars ----
    float sqA[4];
    unsigned hostAp = 0;
    #pragma unroll
    for (int reg = 0; reg < 4; reg++) {
        const int ig = ig0 + q * 4 + reg;
        sqA[reg] = sq[ig];
        hostAp |= ((unsigned)host[ig] & 0xFFu) << (8 * reg);
    }

    // ---- stage segment's sq/host; init colV ----
    {
        const int jcl = min(jr0 + tid, N - 1);    // clamp; extra cols never merged
        if (tid < 256) {
            sqB_s[tid] = sq[jcl];
            hostB_s[tid] = host[jcl];
            #pragma unroll
            for (int i = 0; i < 4; i++) colV[i][tid] = U64MAX;
        }
    }
    __syncthreads();   // sqB_s/hostB_s/colV ready (only barrier before the merge)

    unsigned long long rmin[4] = {U64MAX, U64MAX, U64MAX, U64MAX};

    float4v acc[4];
    #pragma unroll
    for (int ct = 0; ct < 4; ct++) acc[ct] = (float4v)(0.0f);

    for (int it = 0; it < ntiles; ++it) {
        const int tj = tj0 + it;
        const bool diag = (it == 0) && (seg == 0);

        #pragma unroll
        for (int k = 0; k < 8; k++) {
            const int slot = k & 1;
            if (k < 7) loadB(slot ^ 1, tj, k + 1);
            else if (it + 1 < ntiles) loadB(slot ^ 1, tj + 1, 0);
            __builtin_amdgcn_sched_barrier(0);   // pin load batch above the MFMAs
            // pass order per acc: hh, hl, lh within chunk k; chunks ascending ->
            // bit-identical accumulation to all prior revs.
            #pragma unroll
            for (int ct = 0; ct < 4; ct++)
                acc[ct] = __builtin_amdgcn_mfma_f32_16x16x32_bf16(aH[k], bH[slot][ct], acc[ct], 0, 0, 0);
            #pragma unroll
            for (int ct = 0; ct < 4; ct++)
                acc[ct] = __builtin_amdgcn_mfma_f32_16x16x32_bf16(aH[k], bL[slot][ct], acc[ct], 0, 0, 0);
            #pragma unroll
            for (int ct = 0; ct < 4; ct++)
                acc[ct] = __builtin_amdgcn_mfma_f32_16x16x32_bf16(aL[k], bH[slot][ct], acc[ct], 0, 0, 0);
        }

        // ---- per-tile epilogue: packed-u64 dual-sided mins ----
        #pragma unroll
        for (int ct = 0; ct < 4; ct++) {
            const int jl = it * 64 + ct * 16 + tx;    // index into segment range
            const int jg = jr0 + jl;
            const float sb = sqB_s[jl];
            const int   hb = hostB_s[jl];
            unsigned long long cm = U64MAX;
            #pragma unroll
            for (int reg = 0; reg < 4; reg++) {
                const int ig = ig0 + q * 4 + reg;
                const int ha = (int)((hostAp >> (8 * reg)) & 0xFFu);
                const float d = acc[ct][reg];
                const bool masked = (hb == ha) || (diag && (jg <= ig));
                const float rkey = fmaf(-2.0f, d, sb);        // sqB - 2*dot (as before)
                const float ckey = fmaf(-2.0f, d, sqA[reg]);  // sqA - 2*dot (as before)
                const unsigned long long rp = masked ? U64MAX : packKI(rkey, jg);
                const unsigned long long cp = masked ? U64MAX : packKI(ckey, ig);
                rmin[reg] = min64(rmin[reg], rp);
                cm = min64(cm, cp);
            }
            // reduce col-min over q (lane bits 4,5)
            cm = min64(cm, (unsigned long long)__shfl_xor((unsigned long long)cm, 16));
            cm = min64(cm, (unsigned long long)__shfl_xor((unsigned long long)cm, 32));
            if (q == 0) colV[w][jl] = cm;   // each (w, jl) written exactly once
        }
        // reset acc for next tile
        #pragma unroll
        for (int ct = 0; ct < 4; ct++) acc[ct] = (float4v)(0.0f);
    }

    // ---- row-side: reduce over tx (lane bits 0..3), then one atomic per row ----
    #pragma unroll
    for (int reg = 0; reg < 4; reg++) {
        #pragma unroll
        for (int d = 1; d < 16; d <<= 1)
            rmin[reg] = min64(rmin[reg], (unsigned long long)__shfl_xor((unsigned long long)rmin[reg], d));
    }
    if (tx == 0) {
        #pragma unroll
        for (int reg = 0; reg < 4; reg++)
            atomicMin(&M[ig0 + q * 4 + reg], rmin[reg]);
    }

    // ---- col-side merge: 4 wave slots -> one atomic per col ----
    __syncthreads();
    if (tid < ntiles * 64) {
        unsigned long long m = min64(min64(colV[0][tid], colV[1][tid]),
                                     min64(colV[2][tid], colV[3][tid]));
        atomicMin(&M[jr0 + tid], m);
    }
}

// ---------------- K3: extract index and gather e_an rows ----------------
__global__ void finalize_kernel(const unsigned long long* __restrict__ M,
                                const float* __restrict__ E, float* __restrict__ out_an) {
    int row = blockIdx.x;
    int t = threadIdx.x;   // 64
    int idx = (int)(unsigned)(M[row] & 0xFFFFFFFFull);
    float4 v = *(const float4*)&E[(size_t)idx * D + t * 4];
    *(float4*)&out_an[(size_t)row * D + t * 4] = v;
}

extern "C" void kernel_launch(void* const* d_in, const int* in_sizes, int n_in,
                              void* d_out, int out_size, void* d_ws, size_t ws_size,
                              hipStream_t stream) {
    const float* e_actv = (const float*)d_in[0];
    const float* e_ap   = (const float*)d_in[1];
    const int*   host   = (const int*)d_in[2];
    float* out = (float*)d_out;

    // workspace: M u64[N] | sq f32[N] | Ehi bf16[N*D] | Elo bf16[N*D]  (~8.3 MB)
    unsigned long long* M = (unsigned long long*)d_ws;
    float*  sq  = (float*)(M + N);
    ushort* Ehi = (ushort*)(sq + N);
    ushort* Elo = Ehi + (size_t)N * D;

    prep_kernel<<<1024, 256, 0, stream>>>(
        (const float4*)e_actv, (const float4*)e_ap, (float4*)out,
        sq, Ehi, Elo, M);
    argmin_sym<<<NBLK2, 256, 0, stream>>>(Ehi, Elo, host, sq, M);
    finalize_kernel<<<N, 64, 0, stream>>>(M, e_actv, out + 2 * (size_t)N * D);
}

// Round 8
// 169.338 us; speedup vs baseline: 1.3332x; 1.3332x over previous
//
#include <hip/hip_runtime.h>
#include <hip/hip_bf16.h>
#include <cmath>
#include <cstddef>

#define N 8192
#define D 256
#define BIR 128                 // rows per block tile
#define BJC 64                  // cols per block tile
#define NBI (N / BIR)           // 64 row bands
#define NBLK 4160               // sum over ti of (128 - 2*ti) = ti*(129-ti) at 64

typedef __attribute__((ext_vector_type(8))) short short8;   // 8 bf16 = one MFMA A/B frag
typedef __attribute__((ext_vector_type(4))) float float4v;  // MFMA C/D frag

__device__ inline ushort f2bf(float x) {
    __hip_bfloat16 h = __float2bfloat16(x);
    return __builtin_bit_cast(ushort, h);
}
__device__ inline float bf2f(ushort u) {
    __hip_bfloat16 h = __builtin_bit_cast(__hip_bfloat16, u);
    return __bfloat162float(h);
}

// sortable pack: (monotone-uint(key) << 32) | idx  -> atomicMin == argmin, lowest-idx tie-break
__device__ inline unsigned long long packKI(float k, int idx) {
    unsigned u = __float_as_uint(k);
    u = (u & 0x80000000u) ? ~u : (u | 0x80000000u);
    return ((unsigned long long)u << 32) | (unsigned)idx;
}

// S(t) = blocks before row band t: t * (129 - t)
__device__ inline int bandS(int t) { return t * (129 - t); }

// ============================================================================
// Frag-tiled bf16 layout (unchanged): frag for (16-row group g, k-chunk k, lane)
// at ushort offset (g*8 + k)*512 + lane*8 -> wave frag load = uniform base +
// lane*16B: one coalesced 1 KB dwordx4.
// ============================================================================

// ---------------- K1: fused prep — M init, copies, sqnorm, frag-tiled bf16 hi/lo split ----
// grid MUST be 1024 x 256 (phase C uses exactly 4096 waves, one 16x32 tile each).
__global__ void prep_kernel(const float4* __restrict__ a, const float4* __restrict__ p,
                            float4* __restrict__ out, float* __restrict__ sq,
                            ushort* __restrict__ Ehi, ushort* __restrict__ Elo,
                            unsigned long long* __restrict__ M) {
    const int gsz = gridDim.x * blockDim.x;          // 262144, multiple of 64
    const int g0 = blockIdx.x * blockDim.x + threadIdx.x;
    const int total = N * D / 4;                     // 524288 float4

    // phase A: e_actv copy + per-row sqnorm (one row per wave per iter: 64 float4 = 1 row)
    for (int idx = g0; idx < total; idx += gsz) {
        float4 v = a[idx];
        out[idx] = v;
        float s = v.x * v.x + v.y * v.y + v.z * v.z + v.w * v.w;
        #pragma unroll
        for (int off = 32; off; off >>= 1) s += __shfl_down(s, off);
        if ((threadIdx.x & 63) == 0) sq[idx >> 6] = s;
    }
    // phase B: e_ap plain copy into second output slot
    for (int idx = g0; idx < total; idx += gsz) out[total + idx] = p[idx];

    // phase C: frag-tiled hi/lo split. One wave per (r16, ktc) tile of 16 rows x 32 k.
    {
        const int w = g0 >> 6;           // global wave id, 0..4095
        if (w < 4096) {
            const int lane = threadIdx.x & 63;
            const int tx = lane & 15;
            const int q  = lane >> 4;
            const int r16 = w >> 3;      // 0..511
            const int ktc = w & 7;       // 0..7
            const int row = r16 * 16 + tx;
            const float4 v0 = a[row * 64 + ktc * 8 + q * 2];
            const float4 v1 = a[row * 64 + ktc * 8 + q * 2 + 1];
            float e[8] = {v0.x, v0.y, v0.z, v0.w, v1.x, v1.y, v1.z, v1.w};
            short8 hs, ls;
            #pragma unroll
            for (int j = 0; j < 8; j++) {
                ushort h = f2bf(e[j]);
                ushort l = f2bf(e[j] - bf2f(h));
                hs[j] = (short)h;
                ls[j] = (short)l;
            }
            const size_t off = (size_t)(r16 * 8 + ktc) * 512 + lane * 8;
            *(short8*)&Ehi[off] = hs;
            *(short8*)&Elo[off] = ls;
        }
    }
    // M init
    for (int i = g0; i < N; i += gsz) M[i] = 0xFFFFFFFFFFFFFFFFull;
}

// ---------------- K2: 128x64 tiles, minimal-liveness single-buffered chunks ----------
// Coverage identical to round 5 (verified): blocks (ti, tj) over 128-row bands x
// 64-col tiles with tj >= 2*ti; strict upper triangle via (jg<=ig) masks.
// K-loop: per chunk, ALL 12 loads issued back-to-back -> sched_barrier ->
// 24 MFMAs -> sched_barrier. Single-buffered (no dbuf): peak liveness =
// 12 frags (48 VGPR) + 32 acc + misc ~ 110 -> fits the 128-reg cap of
// __launch_bounds__(256,4) with NO spill -> 4 waves/SIMD to hide the one
// exposed per-chunk latency. (r5/r6 showed the allocator spills rather than
// honor bigger pipelines; this schedule is sized to what it will keep.)
// Per-acc MFMA order (hh,hl,lh per chunk, chunks ascending) and all keys/masks
// identical to prior passing revs -> bit-identical argmin indices.
__launch_bounds__(256, 4)
__global__ void argmin_sym(const ushort* __restrict__ Ehi, const ushort* __restrict__ Elo,
                           const int* __restrict__ host, const float* __restrict__ sq,
                           unsigned long long* __restrict__ M) {
    // XCD swizzle (4160 = 8*520, bijective) then decode b -> (ti, tj), tj >= 2*ti
    const int b0 = blockIdx.x;
    const int b = (b0 & 7) * (NBLK / 8) + (b0 >> 3);
    int ti = (int)floor((129.0 - sqrt(129.0 * 129.0 - 4.0 * (double)b)) * 0.5);
    while (bandS(ti + 1) <= b) ti++;
    while (bandS(ti) > b) ti--;
    const int tj = 2 * ti + (b - bandS(ti));

    __shared__ float sqA_s[BIR];
    __shared__ float sqB_s[BJC];
    __shared__ int   hostB_s[BJC];
    __shared__ float rowV[2 * BIR]; __shared__ int rowI[2 * BIR];
    __shared__ float colV[2 * BJC]; __shared__ int colI[2 * BJC];

    const int ib0 = ti * BIR;
    const int jb0 = tj * BJC;
    const int tid = threadIdx.x;
    const int lane = tid & 63;
    const int wave = tid >> 6;      // 0..3
    const int wrow = wave >> 1;     // 0..1  (64-row half)
    const int wcol = wave & 1;      // 0..1  (32-col half)
    const int tx = lane & 15;       // 0..15
    const int q  = lane >> 4;       // 0..3

    // epilogue scalars (consumed only after the pre-epilogue barrier)
    if (tid < BIR) sqA_s[tid] = sq[ib0 + tid];
    if (tid < BJC) {
        sqB_s[tid] = sq[jb0 + tid];
        hostB_s[tid] = host[jb0 + tid];
    }

    // hostA packed per rt: 4 bytes = hosts of rows (rt,reg) for this lane (host < 64)
    unsigned hostAp[4];
    #pragma unroll
    for (int rt = 0; rt < 4; rt++) {
        unsigned p = 0;
        #pragma unroll
        for (int reg = 0; reg < 4; reg++) {
            int hv = host[ib0 + wrow * 64 + rt * 16 + q * 4 + reg];
            p |= ((unsigned)hv & 0xFFu) << (8 * reg);
        }
        hostAp[rt] = p;
    }

    float4v acc[4][2];   // [rt][ct] — 32 f32/lane
    #pragma unroll
    for (int rt = 0; rt < 4; rt++)
        #pragma unroll
        for (int ct = 0; ct < 2; ct++) acc[rt][ct] = (float4v)(0.0f);

    // frag-tile 16-row-group bases
    const int pA = (ib0 >> 4) + wrow * 4;   // + rt (0..3)
    const int pB = (jb0 >> 4) + wcol * 2;   // + ct (0..1)
    const int lo8 = lane * 8;

    // single-buffered chunk frags: 12 frags = 48 VGPR peak
    short8 aH[4], aL[4], bH[2], bL[2];

    #pragma unroll
    for (int k = 0; k < 8; k++) {
        // batch all 12 loads of chunk k back-to-back (one exposed latency/chunk)
        #pragma unroll
        for (int rt = 0; rt < 4; rt++) {
            const int o = ((pA + rt) * 8 + k) * 512 + lo8;
            aH[rt] = *(const short8*)&Ehi[o];
            aL[rt] = *(const short8*)&Elo[o];
        }
        #pragma unroll
        for (int ct = 0; ct < 2; ct++) {
            const int o = ((pB + ct) * 8 + k) * 512 + lo8;
            bH[ct] = *(const short8*)&Ehi[o];
            bL[ct] = *(const short8*)&Elo[o];
        }
        __builtin_amdgcn_sched_barrier(0);   // loads stay above, batched
        #pragma unroll
        for (int rt = 0; rt < 4; rt++)
            #pragma unroll
            for (int ct = 0; ct < 2; ct++)
                acc[rt][ct] = __builtin_amdgcn_mfma_f32_16x16x32_bf16(aH[rt], bH[ct], acc[rt][ct], 0, 0, 0);
        #pragma unroll
        for (int rt = 0; rt < 4; rt++)
            #pragma unroll
            for (int ct = 0; ct < 2; ct++)
                acc[rt][ct] = __builtin_amdgcn_mfma_f32_16x16x32_bf16(aH[rt], bL[ct], acc[rt][ct], 0, 0, 0);
        #pragma unroll
        for (int rt = 0; rt < 4; rt++)
            #pragma unroll
            for (int ct = 0; ct < 2; ct++)
                acc[rt][ct] = __builtin_amdgcn_mfma_f32_16x16x32_bf16(aL[rt], bH[ct], acc[rt][ct], 0, 0, 0);
        __builtin_amdgcn_sched_barrier(0);   // next chunk's loads may not hoist above
    }

    // ---- epilogue: dual-sided argmin (identical to round 5, verified) ----
    __syncthreads();   // orders the sq/host staging before reads (only block barrier)

    // rows side: per lane's 16 rows, min over its 2 ct entries, then over tx
    #pragma unroll
    for (int rt = 0; rt < 4; rt++) {
        unsigned hp = hostAp[rt];
        #pragma unroll
        for (int reg = 0; reg < 4; reg++) {
            int il = wrow * 64 + rt * 16 + q * 4 + reg;
            int ig = ib0 + il;
            int ha = (int)((hp >> (8 * reg)) & 0xFFu);
            float v = 3.0e38f; int ix = 0x7fffffff;
            #pragma unroll
            for (int ct = 0; ct < 2; ct++) {
                int jl = wcol * 32 + ct * 16 + tx;
                int jg = jb0 + jl;
                float key = sqB_s[jl] - 2.0f * acc[rt][ct][reg];
                bool masked = (hostB_s[jl] == ha) || (jg <= ig);   // strict upper: i<j only
                if (!masked && (key < v || (key == v && jg < ix))) { v = key; ix = jg; }
            }
            #pragma unroll
            for (int d = 1; d < 16; d <<= 1) {
                float ov = __shfl_xor(v, d);
                int   oi = __shfl_xor(ix, d);
                if (ov < v || (ov == v && oi < ix)) { v = ov; ix = oi; }
            }
            if (tx == 0) { rowV[il * 2 + wcol] = v; rowI[il * 2 + wcol] = ix; }
        }
    }

    // cols side (always on): per lane's 2 cols, min over 16 row entries, then over q
    #pragma unroll
    for (int ct = 0; ct < 2; ct++) {
        int jl = wcol * 32 + ct * 16 + tx;
        int jg = jb0 + jl;
        int hb = hostB_s[jl];
        float v = 3.0e38f; int ix = 0x7fffffff;
        #pragma unroll
        for (int rt = 0; rt < 4; rt++) {
            unsigned hp = hostAp[rt];
            #pragma unroll
            for (int reg = 0; reg < 4; reg++) {
                int il = wrow * 64 + rt * 16 + q * 4 + reg;
                int ig = ib0 + il;
                bool masked = ((int)((hp >> (8 * reg)) & 0xFFu) == hb) || (ig >= jg);
                float key = sqA_s[il] - 2.0f * acc[rt][ct][reg];
                if (!masked && (key < v || (key == v && ig < ix))) { v = key; ix = ig; }
            }
        }
        #pragma unroll
        for (int d = 16; d < 64; d <<= 1) {
            float ov = __shfl_xor(v, d);
            int   oi = __shfl_xor(ix, d);
            if (ov < v || (ov == v && oi < ix)) { v = ov; ix = oi; }
        }
        if (q == 0) { colV[jl * 2 + wrow] = v; colI[jl * 2 + wrow] = ix; }
    }

    __syncthreads();
    if (tid < BIR) {
        float v0 = rowV[tid * 2];     int x0 = rowI[tid * 2];
        float v1 = rowV[tid * 2 + 1]; int x1 = rowI[tid * 2 + 1];
        if (v1 < v0 || (v1 == v0 && x1 < x0)) { v0 = v1; x0 = x1; }
        atomicMin(&M[ib0 + tid], packKI(v0, x0));
    }
    if (tid < BJC) {
        float w0 = colV[tid * 2];     int y0 = colI[tid * 2];
        float w1 = colV[tid * 2 + 1]; int y1 = colI[tid * 2 + 1];
        if (w1 < w0 || (w1 == w0 && y1 < y0)) { w0 = w1; y0 = y1; }
        atomicMin(&M[jb0 + tid], packKI(w0, y0));
    }
}

// ---------------- K3: extract index and gather e_an rows ----------------
__global__ void finalize_kernel(const unsigned long long* __restrict__ M,
                                const float* __restrict__ E, float* __restrict__ out_an) {
    int row = blockIdx.x;
    int t = threadIdx.x;   // 64
    int idx = (int)(unsigned)(M[row] & 0xFFFFFFFFull);
    float4 v = *(const float4*)&E[(size_t)idx * D + t * 4];
    *(float4*)&out_an[(size_t)row * D + t * 4] = v;
}

extern "C" void kernel_launch(void* const* d_in, const int* in_sizes, int n_in,
                              void* d_out, int out_size, void* d_ws, size_t ws_size,
                              hipStream_t stream) {
    const float* e_actv = (const float*)d_in[0];
    const float* e_ap   = (const float*)d_in[1];
    const int*   host   = (const int*)d_in[2];
    float* out = (float*)d_out;

    // workspace: M u64[N] | sq f32[N] | Ehi bf16[N*D] | Elo bf16[N*D]  (~8.3 MB)
    unsigned long long* M = (unsigned long long*)d_ws;
    float*  sq  = (float*)(M + N);
    ushort* Ehi = (ushort*)(sq + N);
    ushort* Elo = Ehi + (size_t)N * D;

    prep_kernel<<<1024, 256, 0, stream>>>(
        (const float4*)e_actv, (const float4*)e_ap, (float4*)out,
        sq, Ehi, Elo, M);
    argmin_sym<<<NBLK, 256, 0, stream>>>(Ehi, Elo, host, sq, M);
    finalize_kernel<<<N, 64, 0, stream>>>(M, e_actv, out + 2 * (size_t)N * D);
}

// Round 9
// 166.360 us; speedup vs baseline: 1.3571x; 1.0179x over previous
//
#include <hip/hip_runtime.h>
#include <hip/hip_bf16.h>
#include <cmath>
#include <cstddef>

#define N 8192
#define D 256
#define BIR 128                 // rows per block tile
#define BJC 64                  // cols per block tile
#define NBLK 4160               // #{(ti,tj): ti<64, 2ti<=tj<128} = 8 * 520

typedef __attribute__((ext_vector_type(8))) short short8;   // 8 bf16 = one MFMA A/B frag
typedef __attribute__((ext_vector_type(4))) float float4v;  // MFMA C/D frag

__device__ inline ushort f2bf(float x) {
    __hip_bfloat16 h = __float2bfloat16(x);
    return __builtin_bit_cast(ushort, h);
}
__device__ inline float bf2f(ushort u) {
    __hip_bfloat16 h = __builtin_bit_cast(__hip_bfloat16, u);
    return __bfloat162float(h);
}

// sortable pack: (monotone-uint(key) << 32) | idx  -> atomicMin == argmin, lowest-idx tie-break
__device__ inline unsigned long long packKI(float k, int idx) {
    unsigned u = __float_as_uint(k);
    u = (u & 0x80000000u) ? ~u : (u | 0x80000000u);
    return ((unsigned long long)u << 32) | (unsigned)idx;
}

// ============================================================================
// Frag-tiled bf16 layout (unchanged): frag for (16-row group g, k-chunk k, lane)
// at ushort offset (g*8 + k)*512 + lane*8 -> wave frag load = uniform base +
// lane*16B: one coalesced 1 KB dwordx4.
// ============================================================================

// ---------------- K1: fused prep — M init, copies, sqnorm, frag-tiled bf16 hi/lo split ----
// grid MUST be 1024 x 256 (phase C uses exactly 4096 waves, one 16x32 tile each).
__global__ void prep_kernel(const float4* __restrict__ a, const float4* __restrict__ p,
                            float4* __restrict__ out, float* __restrict__ sq,
                            ushort* __restrict__ Ehi, ushort* __restrict__ Elo,
                            unsigned long long* __restrict__ M) {
    const int gsz = gridDim.x * blockDim.x;          // 262144, multiple of 64
    const int g0 = blockIdx.x * blockDim.x + threadIdx.x;
    const int total = N * D / 4;                     // 524288 float4

    // phase A: e_actv copy + per-row sqnorm (one row per wave per iter: 64 float4 = 1 row)
    for (int idx = g0; idx < total; idx += gsz) {
        float4 v = a[idx];
        out[idx] = v;
        float s = v.x * v.x + v.y * v.y + v.z * v.z + v.w * v.w;
        #pragma unroll
        for (int off = 32; off; off >>= 1) s += __shfl_down(s, off);
        if ((threadIdx.x & 63) == 0) sq[idx >> 6] = s;
    }
    // phase B: e_ap plain copy into second output slot
    for (int idx = g0; idx < total; idx += gsz) out[total + idx] = p[idx];

    // phase C: frag-tiled hi/lo split. One wave per (r16, ktc) tile of 16 rows x 32 k.
    {
        const int w = g0 >> 6;           // global wave id, 0..4095
        if (w < 4096) {
            const int lane = threadIdx.x & 63;
            const int tx = lane & 15;
            const int q  = lane >> 4;
            const int r16 = w >> 3;      // 0..511
            const int ktc = w & 7;       // 0..7
            const int row = r16 * 16 + tx;
            const float4 v0 = a[row * 64 + ktc * 8 + q * 2];
            const float4 v1 = a[row * 64 + ktc * 8 + q * 2 + 1];
            float e[8] = {v0.x, v0.y, v0.z, v0.w, v1.x, v1.y, v1.z, v1.w};
            short8 hs, ls;
            #pragma unroll
            for (int j = 0; j < 8; j++) {
                ushort h = f2bf(e[j]);
                ushort l = f2bf(e[j] - bf2f(h));
                hs[j] = (short)h;
                ls[j] = (short)l;
            }
            const size_t off = (size_t)(r16 * 8 + ktc) * 512 + lane * 8;
            *(short8*)&Ehi[off] = hs;
            *(short8*)&Elo[off] = ls;
        }
    }
    // M init
    for (int i = g0; i < N; i += gsz) M[i] = 0xFFFFFFFFFFFFFFFFull;
}

// ---------------- K2: 128x64 tiles, single-buffered chunks, band-group L2 enumeration ----
// Identical compute/epilogue to round 8 (verified, 99us). Changes:
//  (1) Block enumeration: bands grouped by 16 (g=0..3), columns tj-major within
//      group -> the <=16 blocks sharing a B tile are ADJACENT in b, and each
//      XCD's contiguous 520-block range has working set ~2MB A + hot B < 4MB L2.
//      (r8's band-major order streamed 4-8MB of B per band through L2:
//      FETCH_SIZE=93.5MB for an 8.4MB dataset -> 700-900cy load latency.)
//      Same (ti,tj) set (tj>=2ti), counts 1808+1296+784+272=4160; atomicMin
//      order-independent -> bit-identical results.
//  (2) Frag loads via byte offsets incremented by +1024/chunk (base+voffset
//      form) -> removes per-chunk address recompute forced by sched_barrier.
__launch_bounds__(256, 4)
__global__ void argmin_sym(const ushort* __restrict__ Ehi, const ushort* __restrict__ Elo,
                           const int* __restrict__ host, const float* __restrict__ sq,
                           unsigned long long* __restrict__ M) {
    // XCD swizzle (4160 = 8*520, bijective)
    const int b0 = blockIdx.x;
    const int b = (b0 & 7) * (NBLK / 8) + (b0 >> 3);

    // decode b -> (band group g of 16 bands, column d, band-in-group i), tj-major:
    // group g covers ti=16g..16g+15, tj = 32g + d; column d has cnt=min(16, d/2+1)
    // rows (constraint tj>=2ti <=> i<=d/2). Ramp prefix P(2m)=m^2+m, P(2m+1)=(m+1)^2,
    // ramp ends at d=30 (P=240); steady region: 16 rows/column.
    int g, p;
    if (b < 1808)      { g = 0; p = b; }
    else if (b < 3104) { g = 1; p = b - 1808; }
    else if (b < 3888) { g = 2; p = b - 3104; }
    else               { g = 3; p = b - 3888; }
    int d, i;
    if (p >= 240) {
        d = 30 + ((p - 240) >> 4);
        i = (p - 240) & 15;
    } else {
        int m = (int)sqrtf((float)p);
        while (m * m > p) m--;
        while ((m + 1) * (m + 1) <= p) m++;
        if (p >= m * m + m) { d = 2 * m;     i = p - (m * m + m); }
        else                { d = 2 * m - 1; i = p - m * m; }
    }
    const int ti = 16 * g + i;
    const int tj = 32 * g + d;

    __shared__ float sqA_s[BIR];
    __shared__ float sqB_s[BJC];
    __shared__ int   hostB_s[BJC];
    __shared__ float rowV[2 * BIR]; __shared__ int rowI[2 * BIR];
    __shared__ float colV[2 * BJC]; __shared__ int colI[2 * BJC];

    const int ib0 = ti * BIR;
    const int jb0 = tj * BJC;
    const int tid = threadIdx.x;
    const int lane = tid & 63;
    const int wave = tid >> 6;      // 0..3
    const int wrow = wave >> 1;     // 0..1  (64-row half)
    const int wcol = wave & 1;      // 0..1  (32-col half)
    const int tx = lane & 15;       // 0..15
    const int q  = lane >> 4;       // 0..3

    // epilogue scalars (consumed only after the pre-epilogue barrier)
    if (tid < BIR) sqA_s[tid] = sq[ib0 + tid];
    if (tid < BJC) {
        sqB_s[tid] = sq[jb0 + tid];
        hostB_s[tid] = host[jb0 + tid];
    }

    // hostA packed per rt: 4 bytes = hosts of rows (rt,reg) for this lane (host < 64)
    unsigned hostAp[4];
    #pragma unroll
    for (int rt = 0; rt < 4; rt++) {
        unsigned pk = 0;
        #pragma unroll
        for (int reg = 0; reg < 4; reg++) {
            int hv = host[ib0 + wrow * 64 + rt * 16 + q * 4 + reg];
            pk |= ((unsigned)hv & 0xFFu) << (8 * reg);
        }
        hostAp[rt] = pk;
    }

    float4v acc[4][2];   // [rt][ct] — 32 f32/lane
    #pragma unroll
    for (int rt = 0; rt < 4; rt++)
        #pragma unroll
        for (int ct = 0; ct < 2; ct++) acc[rt][ct] = (float4v)(0.0f);

    // frag-tile 16-row-group bases
    const int pA = (ib0 >> 4) + wrow * 4;   // + rt (0..3)
    const int pB = (jb0 >> 4) + wcol * 2;   // + ct (0..1)
    const int lo8 = lane * 8;

    // byte offsets, incremented +1024/chunk (frag stride per k): base+voffset loads,
    // no per-chunk address recompute inside the fenced regions.
    int obA[4], obB[2];
    #pragma unroll
    for (int rt = 0; rt < 4; rt++) obA[rt] = (((pA + rt) * 8) * 512 + lo8) * 2;
    #pragma unroll
    for (int ct = 0; ct < 2; ct++) obB[ct] = (((pB + ct) * 8) * 512 + lo8) * 2;
    const char* EhiB = (const char*)Ehi;
    const char* EloB = (const char*)Elo;

    // single-buffered chunk frags: 12 frags = 48 VGPR peak
    short8 aH[4], aL[4], bH[2], bL[2];

    #pragma unroll
    for (int k = 0; k < 8; k++) {
        // batch all 12 loads of chunk k back-to-back (one exposed latency/chunk)
        #pragma unroll
        for (int rt = 0; rt < 4; rt++) {
            aH[rt] = *(const short8*)(EhiB + obA[rt]);
            aL[rt] = *(const short8*)(EloB + obA[rt]);
        }
        #pragma unroll
        for (int ct = 0; ct < 2; ct++) {
            bH[ct] = *(const short8*)(EhiB + obB[ct]);
            bL[ct] = *(const short8*)(EloB + obB[ct]);
        }
        #pragma unroll
        for (int rt = 0; rt < 4; rt++) obA[rt] += 1024;
        #pragma unroll
        for (int ct = 0; ct < 2; ct++) obB[ct] += 1024;
        __builtin_amdgcn_sched_barrier(0);   // loads stay above, batched
        #pragma unroll
        for (int rt = 0; rt < 4; rt++)
            #pragma unroll
            for (int ct = 0; ct < 2; ct++)
                acc[rt][ct] = __builtin_amdgcn_mfma_f32_16x16x32_bf16(aH[rt], bH[ct], acc[rt][ct], 0, 0, 0);
        #pragma unroll
        for (int rt = 0; rt < 4; rt++)
            #pragma unroll
            for (int ct = 0; ct < 2; ct++)
                acc[rt][ct] = __builtin_amdgcn_mfma_f32_16x16x32_bf16(aH[rt], bL[ct], acc[rt][ct], 0, 0, 0);
        #pragma unroll
        for (int rt = 0; rt < 4; rt++)
            #pragma unroll
            for (int ct = 0; ct < 2; ct++)
                acc[rt][ct] = __builtin_amdgcn_mfma_f32_16x16x32_bf16(aL[rt], bH[ct], acc[rt][ct], 0, 0, 0);
        __builtin_amdgcn_sched_barrier(0);   // next chunk's loads may not hoist above
    }

    // ---- epilogue: dual-sided argmin (identical to rounds 5/8, verified) ----
    __syncthreads();   // orders the sq/host staging before reads (only block barrier)

    // rows side: per lane's 16 rows, min over its 2 ct entries, then over tx
    #pragma unroll
    for (int rt = 0; rt < 4; rt++) {
        unsigned hp = hostAp[rt];
        #pragma unroll
        for (int reg = 0; reg < 4; reg++) {
            int il = wrow * 64 + rt * 16 + q * 4 + reg;
            int ig = ib0 + il;
            int ha = (int)((hp >> (8 * reg)) & 0xFFu);
            float v = 3.0e38f; int ix = 0x7fffffff;
            #pragma unroll
            for (int ct = 0; ct < 2; ct++) {
                int jl = wcol * 32 + ct * 16 + tx;
                int jg = jb0 + jl;
                float key = sqB_s[jl] - 2.0f * acc[rt][ct][reg];
                bool masked = (hostB_s[jl] == ha) || (jg <= ig);   // strict upper: i<j only
                if (!masked && (key < v || (key == v && jg < ix))) { v = key; ix = jg; }
            }
            #pragma unroll
            for (int dd = 1; dd < 16; dd <<= 1) {
                float ov = __shfl_xor(v, dd);
                int   oi = __shfl_xor(ix, dd);
                if (ov < v || (ov == v && oi < ix)) { v = ov; ix = oi; }
            }
            if (tx == 0) { rowV[il * 2 + wcol] = v; rowI[il * 2 + wcol] = ix; }
        }
    }

    // cols side (always on): per lane's 2 cols, min over 16 row entries, then over q
    #pragma unroll
    for (int ct = 0; ct < 2; ct++) {
        int jl = wcol * 32 + ct * 16 + tx;
        int jg = jb0 + jl;
        int hb = hostB_s[jl];
        float v = 3.0e38f; int ix = 0x7fffffff;
        #pragma unroll
        for (int rt = 0; rt < 4; rt++) {
            unsigned hp = hostAp[rt];
            #pragma unroll
            for (int reg = 0; reg < 4; reg++) {
                int il = wrow * 64 + rt * 16 + q * 4 + reg;
                int ig = ib0 + il;
                bool masked = ((int)((hp >> (8 * reg)) & 0xFFu) == hb) || (ig >= jg);
                float key = sqA_s[il] - 2.0f * acc[rt][ct][reg];
                if (!masked && (key < v || (key == v && ig < ix))) { v = key; ix = ig; }
            }
        }
        #pragma unroll
        for (int dd = 16; dd < 64; dd <<= 1) {
            float ov = __shfl_xor(v, dd);
            int   oi = __shfl_xor(ix, dd);
            if (ov < v || (ov == v && oi < ix)) { v = ov; ix = oi; }
        }
        if (q == 0) { colV[jl * 2 + wrow] = v; colI[jl * 2 + wrow] = ix; }
    }

    __syncthreads();
    if (tid < BIR) {
        float v0 = rowV[tid * 2];     int x0 = rowI[tid * 2];
        float v1 = rowV[tid * 2 + 1]; int x1 = rowI[tid * 2 + 1];
        if (v1 < v0 || (v1 == v0 && x1 < x0)) { v0 = v1; x0 = x1; }
        atomicMin(&M[ib0 + tid], packKI(v0, x0));
    }
    if (tid < BJC) {
        float w0 = colV[tid * 2];     int y0 = colI[tid * 2];
        float w1 = colV[tid * 2 + 1]; int y1 = colI[tid * 2 + 1];
        if (w1 < w0 || (w1 == w0 && y1 < y0)) { w0 = w1; y0 = y1; }
        atomicMin(&M[jb0 + tid], packKI(w0, y0));
    }
}

// ---------------- K3: extract index and gather e_an rows ----------------
__global__ void finalize_kernel(const unsigned long long* __restrict__ M,
                                const float* __restrict__ E, float* __restrict__ out_an) {
    int row = blockIdx.x;
    int t = threadIdx.x;   // 64
    int idx = (int)(unsigned)(M[row] & 0xFFFFFFFFull);
    float4 v = *(const float4*)&E[(size_t)idx * D + t * 4];
    *(float4*)&out_an[(size_t)row * D + t * 4] = v;
}

extern "C" void kernel_launch(void* const* d_in, const int* in_sizes, int n_in,
                              void* d_out, int out_size, void* d_ws, size_t ws_size,
                              hipStream_t stream) {
    const float* e_actv = (const float*)d_in[0];
    const float* e_ap   = (const float*)d_in[1];
    const int*   host   = (const int*)d_in[2];
    float* out = (float*)d_out;

    // workspace: M u64[N] | sq f32[N] | Ehi bf16[N*D] | Elo bf16[N*D]  (~8.3 MB)
    unsigned long long* M = (unsigned long long*)d_ws;
    float*  sq  = (float*)(M + N);
    ushort* Ehi = (ushort*)(sq + N);
    ushort* Elo = Ehi + (size_t)N * D;

    prep_kernel<<<1024, 256, 0, stream>>>(
        (const float4*)e_actv, (const float4*)e_ap, (float4*)out,
        sq, Ehi, Elo, M);
    argmin_sym<<<NBLK, 256, 0, stream>>>(Ehi, Elo, host, sq, M);
    finalize_kernel<<<N, 64, 0, stream>>>(M, e_actv, out + 2 * (size_t)N * D);
}